// Round 2
// baseline (1084.703 us; speedup 1.0000x reference)
//
#include <hip/hip_runtime.h>
#include <math.h>

// BilateralNet round 2: MFMA version.
// 12 conv variants (3 modes x 4 rotations folded into tap-coordinate maps)
// -> per-64-pixel-tile MLP (64->128->192->256->320->4) done as bf16 MFMA GEMMs
//    with activations in LDS (8-channel-chunk layout), weights pre-converted
//    to bf16 in d_ws -> averaged par map -> 5x5 adaptive bilateral filter.
//
// LDS layout: addr_ushort(ch,px) = (ch>>3)*512 + px*8 + (ch&7)
//   -> B-fragment (16x16x32 bf16) = one aligned ds_read_b128 per lane
//   -> D-tile writeback = one ds_write_b64 (4 packed bf16) per lane.

#define NN   160
#define NPIX 25600   // 160*160

typedef __attribute__((ext_vector_type(4))) float float4v;
typedef __attribute__((ext_vector_type(8))) unsigned short ushort8;
typedef __attribute__((ext_vector_type(4))) unsigned short ushort4v;
typedef __attribute__((ext_vector_type(8))) __bf16 bf16x8;

__device__ __forceinline__ int refp(int a) { return (a <= NN - 1) ? a : (2 * (NN - 1) - a); }

__device__ __forceinline__ unsigned short f2b(float f) {
    unsigned int x = __float_as_uint(f);
    return (unsigned short)((x + 0x7FFFu + ((x >> 16) & 1u)) >> 16);  // RNE bf16
}

// ---- weight pre-conversion: fp32 -> bf16 row-major into d_ws ----
// layout (ushort idx): [0,4096) w2 ; [4096,12288) w3 ; [12288,24576) w4 ;
//                      [24576,40960) w5 ; [40960,46080) w6 padded to 16x320
__global__ __launch_bounds__(256) void bnet_wconv_kernel(
    const float* __restrict__ w2, const float* __restrict__ w3,
    const float* __restrict__ w4, const float* __restrict__ w5,
    const float* __restrict__ w6, unsigned short* __restrict__ wb)
{
    const int t = blockIdx.x * 256 + threadIdx.x;  // 46080 threads exactly
    if (t < 4096)       wb[t] = f2b(w2[t]);
    else if (t < 12288) wb[t] = f2b(w3[t - 4096]);
    else if (t < 24576) wb[t] = f2b(w4[t - 12288]);
    else if (t < 40960) wb[t] = f2b(w5[t - 24576]);
    else {
        const int i = t - 40960;         // row*320+col, row<16
        wb[t] = (i < 4 * 320) ? f2b(w6[i]) : (unsigned short)0;
    }
}

// one dense layer: reads X[0..K), writes relu(W X + b) into X[K..K+64)
// wave owns p-tile `ptile`; loops over 4 o-tiles.
template <int K>
__device__ __forceinline__ void mfma_layer(const unsigned short* __restrict__ wb,
                                           const float* __restrict__ bias,
                                           unsigned short* Xs,
                                           int ptile, int lo16, int lq) {
    float4v acc[4];
#pragma unroll
    for (int t = 0; t < 4; ++t)
        acc[t] = *(const float4v*)&bias[t * 16 + lq * 4];

#pragma unroll
    for (int s = 0; s < K / 32; ++s) {
        const int ch = s * 32 + lq * 8;
        const bf16x8 bfrag = __builtin_bit_cast(
            bf16x8, *(const ushort8*)&Xs[(ch >> 3) * 512 + (ptile * 16 + lo16) * 8]);
#pragma unroll
        for (int t = 0; t < 4; ++t) {
            const bf16x8 afrag = __builtin_bit_cast(
                bf16x8, *(const ushort8*)&wb[(t * 16 + lo16) * K + ch]);
            acc[t] = __builtin_amdgcn_mfma_f32_16x16x32_bf16(afrag, bfrag, acc[t], 0, 0, 0);
        }
    }

    // writeback: ch = K + t*16 + lq*4 + r , px = ptile*16 + lo16
    const int px = ptile * 16 + lo16;
#pragma unroll
    for (int t = 0; t < 4; ++t) {
        const int cb = K + t * 16 + lq * 4;
        ushort4v w;
#pragma unroll
        for (int r = 0; r < 4; ++r)
            w[r] = f2b(fmaxf(acc[t][r], 0.0f));
        *(ushort4v*)&Xs[(cb >> 3) * 512 + px * 8 + (cb & 7)] = w;
    }
    __syncthreads();
}

__global__ __launch_bounds__(256, 4) void bnet_mlp_kernel(
    const float* __restrict__ x,
    const float* __restrict__ wx, const float* __restrict__ bx,
    const float* __restrict__ wcs, const float* __restrict__ bcs,
    const float* __restrict__ wc, const float* __restrict__ bc,
    const unsigned short* __restrict__ wb,   // bf16 weights in d_ws
    const float* __restrict__ b2, const float* __restrict__ b3,
    const float* __restrict__ b4, const float* __restrict__ b5,
    const float* __restrict__ b6,
    const float* __restrict__ w1x, const float* __restrict__ w1cs,
    const float* __restrict__ w1c,
    float* __restrict__ par)  // par[ch][b][pix], ch-major; pre-zeroed
{
    __shared__ unsigned short Xs[20480];  // 40 chunks x 1024 B = 40 KB

    const int t = threadIdx.x;
    const int p = t & 63;
    const int lane = t & 63;
    const int lo16 = lane & 15;
    const int lq = lane >> 4;
    const int wave = __builtin_amdgcn_readfirstlane(t >> 6);  // 0..3 = p-tile & conv o-group

    const int bid = blockIdx.x;          // 2400 blocks = 400 tiles * 2 batches * 3 modes
    const int tile = bid % 400;
    const int b = (bid / 400) & 1;
    const int mode = bid / 800;          // 0='x', 1='s', 2='c'

    const int pix = tile * 64 + p;
    const int pi = pix / NN;
    const int pj = pix - pi * NN;
    const float* xb = x + b * NPIX;

    const float* w1 = (mode == 0) ? w1x : (mode == 1) ? w1cs : w1c;
    const float* b1 = (mode == 0) ? bx : (mode == 1) ? bcs : bc;
    int DY[4], DX[4];
    if (mode == 0)      { DY[0]=0; DY[1]=0; DY[2]=1; DY[3]=1;  DX[0]=0; DX[1]=1; DX[2]=0; DX[3]=1; }
    else if (mode == 1) { DY[0]=0; DY[1]=1; DY[2]=1; DY[3]=2;  DX[0]=0; DX[1]=1; DX[2]=2; DX[3]=1; }
    else                { DY[0]=0; DY[1]=0; DY[2]=2; DY[3]=2;  DX[0]=0; DX[1]=2; DX[2]=0; DX[3]=2; }

    const unsigned short* w2b = wb;
    const unsigned short* w3b = wb + 4096;
    const unsigned short* w4b = wb + 12288;
    const unsigned short* w5b = wb + 24576;
    const unsigned short* w6b = wb + 40960;

    float4v acc6 = {0.0f, 0.0f, 0.0f, 0.0f};  // final layer acc, carried over rotations

    for (int k = 0; k < 4; ++k) {
        __syncthreads();  // protect X[0..63] overwrite vs previous rotation's reads

        // ---- stage 1: 4-tap conv; thread owns ch wave*16..+15 at pixel p ----
        float s[4];
#pragma unroll
        for (int tt = 0; tt < 4; ++tt) {
            const int dy = DY[tt], dx = DX[tt];
            int r, c;
            if (k == 0)      { r = refp(pi + dy); c = refp(pj + dx); }
            else if (k == 1) { r = refp(pi + dx); c = (pj >= dy) ? (pj - dy) : (dy - pj); }
            else if (k == 2) { r = (pi >= dy) ? (pi - dy) : (dy - pi);
                               c = (pj >= dx) ? (pj - dx) : (dx - pj); }
            else             { r = (pi >= dx) ? (pi - dx) : (dx - pi); c = refp(pj + dy); }
            s[tt] = xb[r * NN + c];
        }
        ushort8 pk0, pk1;
#pragma unroll
        for (int oo = 0; oo < 16; ++oo) {
            const int o = wave * 16 + oo;
            float cacc = b1[o];
#pragma unroll
            for (int tt = 0; tt < 4; ++tt) cacc = fmaf(w1[o * 4 + tt], s[tt], cacc);
            const unsigned short v = f2b(fmaxf(cacc, 0.0f));
            if (oo < 8) pk0[oo] = v; else pk1[oo - 8] = v;
        }
        *(ushort8*)&Xs[(wave * 2) * 512 + p * 8]     = pk0;
        *(ushort8*)&Xs[(wave * 2 + 1) * 512 + p * 8] = pk1;
        __syncthreads();

        mfma_layer<64 >(w2b, b2, Xs, wave, lo16, lq);
        mfma_layer<128>(w3b, b3, Xs, wave, lo16, lq);
        mfma_layer<192>(w4b, b4, Xs, wave, lo16, lq);
        mfma_layer<256>(w5b, b5, Xs, wave, lo16, lq);

        // ---- final layer: w6 padded [16][320]; accumulate across rotations ----
#pragma unroll
        for (int s6 = 0; s6 < 10; ++s6) {
            const int ch = s6 * 32 + lq * 8;
            const bf16x8 bfrag = __builtin_bit_cast(
                bf16x8, *(const ushort8*)&Xs[(ch >> 3) * 512 + (wave * 16 + lo16) * 8]);
            const bf16x8 afrag = __builtin_bit_cast(
                bf16x8, *(const ushort8*)&w6b[lo16 * 320 + ch]);
            acc6 = __builtin_amdgcn_mfma_f32_16x16x32_bf16(afrag, bfrag, acc6, 0, 0, 0);
        }
        // loop-top __syncthreads() protects Xs reuse
    }

    // D rows 0..3 live in lanes 0..15 (lq==0), reg r = par channel r
    if (lq == 0) {
        const int pixg = tile * 64 + wave * 16 + lo16;
#pragma unroll
        for (int r = 0; r < 4; ++r)
            atomicAdd(&par[(r * 2 + b) * NPIX + pixg], acc6[r] + 4.0f * b6[r]);
    }
}

__global__ __launch_bounds__(256) void bnet_bilateral_kernel(
    const float* __restrict__ x, float* __restrict__ out)
{
    const int tid = blockIdx.x * 256 + threadIdx.x;  // 51200 threads exactly
    const int b = tid / NPIX;
    const int pix = tid - b * NPIX;
    const int pi = pix / NN;
    const int pj = pix - pi * NN;

    float* par = out + 2 * NPIX;
    const float inv12 = 1.0f / 12.0f;
    const float p0 = par[(0 + b) * NPIX + pix] * inv12;
    const float p1 = par[(2 + b) * NPIX + pix] * inv12;
    const float p2 = par[(4 + b) * NPIX + pix] * inv12;
    const float p3 = par[(6 + b) * NPIX + pix] * inv12;

    float sigx = 1.0f / (1.0f + expf(-p0)) + 1e-6f;
    sigx = fminf(fmaxf(sigx, 0.0f), 1.0f);
    float sigy = 1.0f / (1.0f + expf(-p1)) + 1e-6f;
    sigy = fminf(fmaxf(sigy, 0.0f), 1.0f);
    float th = tanhf(p2);
    th = fminf(fmaxf(th, -1.0f), 1.0f);
    float sigr = tanhf(p3) + 1e-6f;
    sigr = fminf(fmaxf(sigr, -1.0f), 1.0f);

    par[(0 + b) * NPIX + pix] = sigx;
    par[(2 + b) * NPIX + pix] = sigy;
    par[(4 + b) * NPIX + pix] = th;
    par[(6 + b) * NPIX + pix] = sigr;

    const float sx = sigx * 20.0f;
    const float sy = sigy * 20.0f;
    const float sr = sigr * 10.0f + 10.0f;

    const float* xb = x + b * NPIX;
    float patch[5][5];
#pragma unroll
    for (int ky = 0; ky < 5; ++ky) {
#pragma unroll
        for (int kx = 0; kx < 5; ++kx) {
            const int r = pi + ky - 2, c = pj + kx - 2;
            patch[ky][kx] = (r >= 0 && r < NN && c >= 0 && c < NN) ? xb[r * NN + c] : 0.0f;
        }
    }

    const float inv2sr2 = 1.0f / (2.0f * sr * sr);
    float num = 0.0f, den = 0.0f;
#pragma unroll
    for (int ky = 0; ky < 5; ++ky) {
#pragma unroll
        for (int kx = 0; kx < 5; ++kx) {
            const float v = patch[ky][kx];
            const float dxv = fabsf(patch[2][kx] - v);
            const float dyv = fabsf(patch[ky][2] - v);
            const float a = sx * dxv;
            const float bb = sy * dyv;
            const float sq = (float)((ky - 2) * (ky - 2) + (kx - 2) * (kx - 2));
            const float kern = expf(-sq * inv2sr2 - 0.5f * (a * a - 2.0f * th * a * bb + bb * bb));
            den += kern;
            num = fmaf(kern, v, num);
        }
    }
    out[tid] = num / den;
}

extern "C" void kernel_launch(void* const* d_in, const int* in_sizes, int n_in,
                              void* d_out, int out_size, void* d_ws, size_t ws_size,
                              hipStream_t stream) {
    const float* x   = (const float*)d_in[0];
    const float* wx  = (const float*)d_in[1];
    const float* bx  = (const float*)d_in[2];
    const float* wc  = (const float*)d_in[3];
    const float* bc  = (const float*)d_in[4];
    const float* wcs = (const float*)d_in[5];
    const float* bcs = (const float*)d_in[6];
    const float* w2  = (const float*)d_in[7];
    const float* b2  = (const float*)d_in[8];
    const float* w3  = (const float*)d_in[9];
    const float* b3  = (const float*)d_in[10];
    const float* w4  = (const float*)d_in[11];
    const float* b4  = (const float*)d_in[12];
    const float* w5  = (const float*)d_in[13];
    const float* b5  = (const float*)d_in[14];
    const float* w6  = (const float*)d_in[15];
    const float* b6  = (const float*)d_in[16];
    float* out = (float*)d_out;
    unsigned short* wb = (unsigned short*)d_ws;  // 46080 ushorts = 92160 B

    // zero the par accumulator region (d_out tail, re-poisoned each launch)
    hipMemsetAsync(out + 2 * NPIX, 0, 8 * NPIX * sizeof(float), stream);

    hipLaunchKernelGGL(bnet_wconv_kernel, dim3(180), dim3(256), 0, stream,
                       w2, w3, w4, w5, w6, wb);

    hipLaunchKernelGGL(bnet_mlp_kernel, dim3(2400), dim3(256), 0, stream,
                       x, wx, bx, wcs, bcs, wc, bc,
                       wb, b2, b3, b4, b5, b6,
                       wx, wcs, wc,
                       out + 2 * NPIX);

    hipLaunchKernelGGL(bnet_bilateral_kernel, dim3(200), dim3(256), 0, stream,
                       x, out);
}

// Round 3
// 193.367 us; speedup vs baseline: 5.6096x; 5.6096x over previous
//
#include <hip/hip_runtime.h>
#include <math.h>

// BilateralNet round 3: weights-in-registers MFMA version.
// Round-2 pathology: per-lane global re-reads of bf16 weights every layer x
// rotation -> 2.65 GB HBM traffic, memory-system bound at 2.6 TB/s.
// Fix: wave w owns o-tile w for ALL layers; its A-fragments are loaded into
// VGPRs ONCE per block (80 VGPR for L2-L5 + 12 for its w6 K-slice) and reused
// across 2 pixel-tiles x 4 rotations x 4 p-tiles. B-fragments come from LDS.
// w6 is K-split across waves; partials reduced via a 4 KB LDS buffer.

#define NN   160
#define NPIX 25600   // 160*160

typedef __attribute__((ext_vector_type(4))) float float4v;
typedef __attribute__((ext_vector_type(8))) unsigned short ushort8;
typedef __attribute__((ext_vector_type(4))) unsigned short ushort4v;
typedef __attribute__((ext_vector_type(8))) __bf16 bf16x8;

__device__ __forceinline__ int refp(int a) { return (a <= NN - 1) ? a : (2 * (NN - 1) - a); }

__device__ __forceinline__ unsigned short f2b(float f) {
    unsigned int x = __float_as_uint(f);
    return (unsigned short)((x + 0x7FFFu + ((x >> 16) & 1u)) >> 16);  // RNE bf16
}

// ---- weight pre-conversion: fp32 -> bf16 row-major into d_ws ----
// layout (ushort idx): [0,4096) w2 ; [4096,12288) w3 ; [12288,24576) w4 ;
//                      [24576,40960) w5 ; [40960,46080) w6 padded to 16x320
__global__ __launch_bounds__(256) void bnet_wconv_kernel(
    const float* __restrict__ w2, const float* __restrict__ w3,
    const float* __restrict__ w4, const float* __restrict__ w5,
    const float* __restrict__ w6, unsigned short* __restrict__ wb)
{
    const int t = blockIdx.x * 256 + threadIdx.x;  // 46080 threads exactly
    if (t < 4096)       wb[t] = f2b(w2[t]);
    else if (t < 12288) wb[t] = f2b(w3[t - 4096]);
    else if (t < 24576) wb[t] = f2b(w4[t - 12288]);
    else if (t < 40960) wb[t] = f2b(w5[t - 24576]);
    else {
        const int i = t - 40960;         // row*320+col, row<16
        wb[t] = (i < 4 * 320) ? f2b(w6[i]) : (unsigned short)0;
    }
}

// one dense layer: reads X[0..K), writes relu(W X + b) into X[K..K+64)
// wave owns o-tile w (A in registers); loops p-tiles in pairs for MFMA ILP.
template <int NCH>  // K = NCH*32 input channels
__device__ __forceinline__ void dense_layer(const ushort8 (&A)[NCH], float4v biasv,
                                            unsigned short* Xs, int w, int lo16, int lq) {
    const int K = NCH * 32;
#pragma unroll
    for (int pp = 0; pp < 2; ++pp) {
        const int px0 = (pp * 2) * 16 + lo16;
        const int px1 = (pp * 2 + 1) * 16 + lo16;
        float4v acc0 = biasv, acc1 = biasv;
#pragma unroll
        for (int s = 0; s < NCH; ++s) {
            const int c8 = s * 4 + lq;
            const bf16x8 bf0 = __builtin_bit_cast(bf16x8, *(const ushort8*)&Xs[c8 * 512 + px0 * 8]);
            const bf16x8 bf1 = __builtin_bit_cast(bf16x8, *(const ushort8*)&Xs[c8 * 512 + px1 * 8]);
            const bf16x8 af  = __builtin_bit_cast(bf16x8, A[s]);
            acc0 = __builtin_amdgcn_mfma_f32_16x16x32_bf16(af, bf0, acc0, 0, 0, 0);
            acc1 = __builtin_amdgcn_mfma_f32_16x16x32_bf16(af, bf1, acc1, 0, 0, 0);
        }
        const int cb = K + w * 16 + lq * 4;
        ushort4v o0, o1;
#pragma unroll
        for (int r = 0; r < 4; ++r) {
            o0[r] = f2b(fmaxf(acc0[r], 0.0f));
            o1[r] = f2b(fmaxf(acc1[r], 0.0f));
        }
        *(ushort4v*)&Xs[(cb >> 3) * 512 + px0 * 8 + (cb & 7)] = o0;
        *(ushort4v*)&Xs[(cb >> 3) * 512 + px1 * 8 + (cb & 7)] = o1;
    }
    __syncthreads();
}

__global__ __launch_bounds__(256) void bnet_mlp_kernel(
    const float* __restrict__ x,
    const float* __restrict__ wx, const float* __restrict__ bx,
    const float* __restrict__ wcs, const float* __restrict__ bcs,
    const float* __restrict__ wc, const float* __restrict__ bc,
    const unsigned short* __restrict__ wb,   // bf16 weights in d_ws
    const float* __restrict__ b2, const float* __restrict__ b3,
    const float* __restrict__ b4, const float* __restrict__ b5,
    const float* __restrict__ b6,
    float* __restrict__ par)  // par[ch][b][pix], ch-major; pre-zeroed
{
    __shared__ unsigned short Xs[20480];    // 40 chunks x 1024 B = 40 KB
    __shared__ float red[4][4][16][4];      // [wave][ptile][px16][r] = 4 KB

    const int t = threadIdx.x;
    const int lane = t & 63;
    const int lo16 = lane & 15;
    const int lq = lane >> 4;
    const int w = __builtin_amdgcn_readfirstlane(t >> 6);  // wave id 0..3 = o-tile

    const int bid = blockIdx.x;          // 1200 blocks = 200 tilegroups * 2 b * 3 modes
    const int tg = bid % 200;
    const int b = (bid / 200) & 1;
    const int mode = bid / 400;          // 0='x', 1='s', 2='c'

    const float* xb = x + b * NPIX;
    const float* w1 = (mode == 0) ? wx : (mode == 1) ? wcs : wc;
    const float* b1 = (mode == 0) ? bx : (mode == 1) ? bcs : bc;
    int DY[4], DX[4];
    if (mode == 0)      { DY[0]=0; DY[1]=0; DY[2]=1; DY[3]=1;  DX[0]=0; DX[1]=1; DX[2]=0; DX[3]=1; }
    else if (mode == 1) { DY[0]=0; DY[1]=1; DY[2]=1; DY[3]=2;  DX[0]=0; DX[1]=1; DX[2]=2; DX[3]=1; }
    else                { DY[0]=0; DY[1]=0; DY[2]=2; DY[3]=2;  DX[0]=0; DX[1]=2; DX[2]=0; DX[3]=2; }

    // ---- stage this wave's A-fragments into registers (once per block) ----
    const int arow = w * 16 + lo16;
    ushort8 a2[2], a3[4], a4[6], a5[8], a6[3];
#pragma unroll
    for (int s = 0; s < 2; ++s) a2[s] = *(const ushort8*)&wb[arow * 64 + s * 32 + lq * 8];
#pragma unroll
    for (int s = 0; s < 4; ++s) a3[s] = *(const ushort8*)&wb[4096 + arow * 128 + s * 32 + lq * 8];
#pragma unroll
    for (int s = 0; s < 6; ++s) a4[s] = *(const ushort8*)&wb[12288 + arow * 192 + s * 32 + lq * 8];
#pragma unroll
    for (int s = 0; s < 8; ++s) a5[s] = *(const ushort8*)&wb[24576 + arow * 256 + s * 32 + lq * 8];
#pragma unroll
    for (int c = 0; c < 3; ++c) {
        const int ch = (3 * w + c) * 32;   // wave w covers w6 K-chunks 3w..3w+2
        if (ch < 320) {
            a6[c] = *(const ushort8*)&wb[40960 + lo16 * 320 + ch + lq * 8];
        } else {
            ushort8 z = {0, 0, 0, 0, 0, 0, 0, 0};
            a6[c] = z;                     // zero A -> zero contribution
        }
    }

    const float4v b2v = *(const float4v*)&b2[w * 16 + lq * 4];
    const float4v b3v = *(const float4v*)&b3[w * 16 + lq * 4];
    const float4v b4v = *(const float4v*)&b4[w * 16 + lq * 4];
    const float4v b5v = *(const float4v*)&b5[w * 16 + lq * 4];

    for (int t2 = 0; t2 < 2; ++t2) {
        const int tile = tg * 2 + t2;
        const int pix = tile * 64 + lane;
        const int pi = pix / NN;
        const int pj = pix - pi * NN;

        float4v acc6[4];                   // w6 partial per p-tile, over rotations
#pragma unroll
        for (int pt = 0; pt < 4; ++pt) { float4v z = {0.f, 0.f, 0.f, 0.f}; acc6[pt] = z; }

        for (int k = 0; k < 4; ++k) {
            __syncthreads();  // protect Xs[ch 0..63] overwrite vs previous reads

            // ---- stage 1: 4-tap conv; thread owns ch w*16..+15 at px=lane ----
            float s4[4];
#pragma unroll
            for (int tt = 0; tt < 4; ++tt) {
                const int dy = DY[tt], dx = DX[tt];
                int r, c;
                if (k == 0)      { r = refp(pi + dy); c = refp(pj + dx); }
                else if (k == 1) { r = refp(pi + dx); c = (pj >= dy) ? (pj - dy) : (dy - pj); }
                else if (k == 2) { r = (pi >= dy) ? (pi - dy) : (dy - pi);
                                   c = (pj >= dx) ? (pj - dx) : (dx - pj); }
                else             { r = (pi >= dx) ? (pi - dx) : (dx - pi); c = refp(pj + dy); }
                s4[tt] = xb[r * NN + c];
            }
            ushort8 pk0, pk1;
#pragma unroll
            for (int oo = 0; oo < 16; ++oo) {
                const int o = w * 16 + oo;
                float cacc = b1[o];
#pragma unroll
                for (int tt = 0; tt < 4; ++tt) cacc = fmaf(w1[o * 4 + tt], s4[tt], cacc);
                const unsigned short v = f2b(fmaxf(cacc, 0.0f));
                if (oo < 8) pk0[oo] = v; else pk1[oo - 8] = v;
            }
            *(ushort8*)&Xs[(w * 2) * 512 + lane * 8]     = pk0;
            *(ushort8*)&Xs[(w * 2 + 1) * 512 + lane * 8] = pk1;
            __syncthreads();

            dense_layer<2>(a2, b2v, Xs, w, lo16, lq);
            dense_layer<4>(a3, b3v, Xs, w, lo16, lq);
            dense_layer<6>(a4, b4v, Xs, w, lo16, lq);
            dense_layer<8>(a5, b5v, Xs, w, lo16, lq);

            // ---- final layer partials: wave w covers K-chunks 3w..3w+2 ----
#pragma unroll
            for (int pt = 0; pt < 4; ++pt) {
                const int px = pt * 16 + lo16;
#pragma unroll
                for (int c = 0; c < 3; ++c) {
                    int chb = (3 * w + c) * 32;
                    chb = (chb < 288) ? chb : 288;   // clamp: A is zero there anyway
                    const int c8 = (chb >> 3) + lq;
                    const bf16x8 bf = __builtin_bit_cast(
                        bf16x8, *(const ushort8*)&Xs[c8 * 512 + px * 8]);
                    const bf16x8 af = __builtin_bit_cast(bf16x8, a6[c]);
                    acc6[pt] = __builtin_amdgcn_mfma_f32_16x16x32_bf16(af, bf, acc6[pt], 0, 0, 0);
                }
            }
            // loop-top __syncthreads() protects Xs reuse
        }

        // ---- reduce w6 partials across waves; rows 0..3 live at lq==0 ----
        if (lq == 0) {
#pragma unroll
            for (int pt = 0; pt < 4; ++pt)
                *(float4v*)&red[w][pt][lo16][0] = acc6[pt];
        }
        __syncthreads();
        if (w == 0) {
            // 64 lanes of wave 0: p-tile = lq, pixel-in-tile = lo16
            float4v sv;
#pragma unroll
            for (int r = 0; r < 4; ++r)
                sv[r] = red[0][lq][lo16][r] + red[1][lq][lo16][r]
                      + red[2][lq][lo16][r] + red[3][lq][lo16][r];
            const int pixg = tile * 64 + lq * 16 + lo16;
#pragma unroll
            for (int r = 0; r < 4; ++r)
                atomicAdd(&par[(r * 2 + b) * NPIX + pixg], sv[r] + 4.0f * b6[r]);
        }
        // next red write is after next tile's full rotation loop (many barriers) -> safe
    }
}

__global__ __launch_bounds__(256) void bnet_bilateral_kernel(
    const float* __restrict__ x, float* __restrict__ out)
{
    const int tid = blockIdx.x * 256 + threadIdx.x;  // 51200 threads exactly
    const int b = tid / NPIX;
    const int pix = tid - b * NPIX;
    const int pi = pix / NN;
    const int pj = pix - pi * NN;

    float* par = out + 2 * NPIX;
    const float inv12 = 1.0f / 12.0f;
    const float p0 = par[(0 + b) * NPIX + pix] * inv12;
    const float p1 = par[(2 + b) * NPIX + pix] * inv12;
    const float p2 = par[(4 + b) * NPIX + pix] * inv12;
    const float p3 = par[(6 + b) * NPIX + pix] * inv12;

    float sigx = 1.0f / (1.0f + expf(-p0)) + 1e-6f;
    sigx = fminf(fmaxf(sigx, 0.0f), 1.0f);
    float sigy = 1.0f / (1.0f + expf(-p1)) + 1e-6f;
    sigy = fminf(fmaxf(sigy, 0.0f), 1.0f);
    float th = tanhf(p2);
    th = fminf(fmaxf(th, -1.0f), 1.0f);
    float sigr = tanhf(p3) + 1e-6f;
    sigr = fminf(fmaxf(sigr, -1.0f), 1.0f);

    par[(0 + b) * NPIX + pix] = sigx;
    par[(2 + b) * NPIX + pix] = sigy;
    par[(4 + b) * NPIX + pix] = th;
    par[(6 + b) * NPIX + pix] = sigr;

    const float sx = sigx * 20.0f;
    const float sy = sigy * 20.0f;
    const float sr = sigr * 10.0f + 10.0f;

    const float* xb = x + b * NPIX;
    float patch[5][5];
#pragma unroll
    for (int ky = 0; ky < 5; ++ky) {
#pragma unroll
        for (int kx = 0; kx < 5; ++kx) {
            const int r = pi + ky - 2, c = pj + kx - 2;
            patch[ky][kx] = (r >= 0 && r < NN && c >= 0 && c < NN) ? xb[r * NN + c] : 0.0f;
        }
    }

    const float inv2sr2 = 1.0f / (2.0f * sr * sr);
    float num = 0.0f, den = 0.0f;
#pragma unroll
    for (int ky = 0; ky < 5; ++ky) {
#pragma unroll
        for (int kx = 0; kx < 5; ++kx) {
            const float v = patch[ky][kx];
            const float dxv = fabsf(patch[2][kx] - v);
            const float dyv = fabsf(patch[ky][2] - v);
            const float a = sx * dxv;
            const float bb = sy * dyv;
            const float sq = (float)((ky - 2) * (ky - 2) + (kx - 2) * (kx - 2));
            const float kern = expf(-sq * inv2sr2 - 0.5f * (a * a - 2.0f * th * a * bb + bb * bb));
            den += kern;
            num = fmaf(kern, v, num);
        }
    }
    out[tid] = num / den;
}

extern "C" void kernel_launch(void* const* d_in, const int* in_sizes, int n_in,
                              void* d_out, int out_size, void* d_ws, size_t ws_size,
                              hipStream_t stream) {
    const float* x   = (const float*)d_in[0];
    const float* wx  = (const float*)d_in[1];
    const float* bx  = (const float*)d_in[2];
    const float* wc  = (const float*)d_in[3];
    const float* bc  = (const float*)d_in[4];
    const float* wcs = (const float*)d_in[5];
    const float* bcs = (const float*)d_in[6];
    const float* w2  = (const float*)d_in[7];
    const float* b2  = (const float*)d_in[8];
    const float* w3  = (const float*)d_in[9];
    const float* b3  = (const float*)d_in[10];
    const float* w4  = (const float*)d_in[11];
    const float* b4  = (const float*)d_in[12];
    const float* w5  = (const float*)d_in[13];
    const float* b5  = (const float*)d_in[14];
    const float* w6  = (const float*)d_in[15];
    const float* b6  = (const float*)d_in[16];
    float* out = (float*)d_out;
    unsigned short* wb = (unsigned short*)d_ws;  // 46080 ushorts = 92160 B

    // zero the par accumulator region (d_out tail, re-poisoned each launch)
    hipMemsetAsync(out + 2 * NPIX, 0, 8 * NPIX * sizeof(float), stream);

    hipLaunchKernelGGL(bnet_wconv_kernel, dim3(180), dim3(256), 0, stream,
                       w2, w3, w4, w5, w6, wb);

    hipLaunchKernelGGL(bnet_mlp_kernel, dim3(1200), dim3(256), 0, stream,
                       x, wx, bx, wcs, bcs, wc, bc,
                       wb, b2, b3, b4, b5, b6,
                       out + 2 * NPIX);

    hipLaunchKernelGGL(bnet_bilateral_kernel, dim3(200), dim3(256), 0, stream,
                       x, out);
}